// Round 5
// baseline (217.982 us; speedup 1.0000x reference)
//
#include <hip/hip_runtime.h>
#include <stdint.h>

// VQ-VAE nearest-codeword quantization, MI355X (gfx950).
// M=16384 rows, D=256 dims, K=8192 codewords.
// argmin_k ||x-c_k||^2 == argmin_k ( ||c_k||^2 - 2 x.c_k )
//
// R5: (a) LDS-FREE main GEMM: K=256 is so short that LDS staging + 16
//     barriers cost more than they save; A-tile (32KB) and Bp (2MB) are
//     L1/L2-resident, so MFMA fragments load straight from global
//     (AITER-flatmm shape: no __shared__, no __syncthreads in K-loop,
//     no bank conflicts, no staging VALU).
// (b) Correctness hardening after R4's absmax=64 (one argmin flip, traced
//     to top-2 kept-set failure): TOP-4 per 512-col split (needs 4
//     simultaneous fp8-error beaters: P~3e-7 dataset-wide), EPS 12->20,
//     and forced-RTNE fp8 conversion (pre-round f32 mantissa to 3 bits so
//     the intrinsic's rounding mode is irrelevant).
// R2/R3 machinery kept: packed (dist_bits&~511)|col9 candidates, fp64
// rescore of EPS-qualifiers (ties -> smaller index, matching np.argmin).

#define M_ROWS 16384
#define D_DIM  256
#define K_CB   8192
#define NSPLIT 16           // 512 codewords per split
#define BM 128
#define BN 128
#define EPS 20.0f

typedef float f32x4 __attribute__((ext_vector_type(4)));
typedef int   int8v __attribute__((ext_vector_type(8)));

__device__ __forceinline__ uint32_t umin32(uint32_t a, uint32_t b) { return a < b ? a : b; }
__device__ __forceinline__ uint32_t umax32(uint32_t a, uint32_t b) { return a > b ? a : b; }

// round f32 to 3 mantissa bits, RTNE (carry into exponent handled by the add)
__device__ __forceinline__ float rtne3(float f) {
  uint32_t u = __float_as_uint(f);
  u = (u + 0x0007FFFFu + ((u >> 20) & 1u)) & 0xFFF00000u;
  return __uint_as_float(u);
}

__device__ __forceinline__ uint32_t fp8x4(const f32x4 v) {
  // pre-rounded values are exactly representable -> intrinsic is exact
  int p = __builtin_amdgcn_cvt_pk_fp8_f32(rtne3(v[0]), rtne3(v[1]), 0, false);
  p = __builtin_amdgcn_cvt_pk_fp8_f32(rtne3(v[2]), rtne3(v[3]), p, true);
  return (uint32_t)p;
}

// ---- fused prep: x -> Ap fp8 (RTNE) ; cb -> Bp fp8 (RTNE) + fp64-exact c2 ----
__global__ __launch_bounds__(256) void prep(const float* __restrict__ x,
                                            const float* __restrict__ cb,
                                            uint8_t* __restrict__ Ap,
                                            uint8_t* __restrict__ Bp,
                                            float* __restrict__ c2) {
  const int w = threadIdx.x >> 6, lane = threadIdx.x & 63;
  if (blockIdx.x < M_ROWS / 4) {
    const int row = blockIdx.x * 4 + w;                 // one wave per x row
    const f32x4 v = *(const f32x4*)(x + (size_t)row * D_DIM + lane * 4);
    *(uint32_t*)(Ap + (size_t)row * D_DIM + lane * 4) = fp8x4(v);
  } else {
    const int row = (blockIdx.x - M_ROWS / 4) * 4 + w;  // one wave per codeword
    const f32x4 v = *(const f32x4*)(cb + (size_t)row * D_DIM + lane * 4);
    *(uint32_t*)(Bp + (size_t)row * D_DIM + lane * 4) = fp8x4(v);
    double s = 0.0;
#pragma unroll
    for (int t = 0; t < 4; ++t) s += (double)v[t] * (double)v[t];
#pragma unroll
    for (int m = 1; m < 64; m <<= 1) s += __shfl_xor(s, m, 64);
    if (lane == 0) c2[row] = (float)s;                  // fp64-exact ||c||^2
  }
}

// -------- main: LDS-free fp8 K=256 GEMM + fused packed top-4 per split --------
__global__ __launch_bounds__(256, 2) void vq_main(const uint8_t* __restrict__ Ap,
                                                  const uint8_t* __restrict__ Bp,
                                                  const float* __restrict__ c2,
                                                  uint4* __restrict__ part) {
  __shared__ uint32_t sred[BM][8];    // 4 KB: [row][wn*4+slot] final merge only

  const int tid  = threadIdx.x;
  const int w    = tid >> 6;
  const int lane = tid & 63;
  const int wm   = w >> 1;            // 2x2 wave grid over the 128x128 tile
  const int wn   = w & 1;

  const int rowBase = blockIdx.x * BM;
  const int nBase   = blockIdx.y * (K_CB / NSPLIT);   // split base (512 cols)

  const int fr = lane & 15;           // frag: m (or n) index
  const int fq = lane >> 4;           // frag: k-quarter (32 contiguous bytes)

  // per-lane frag base pointers (k-chunk = fq*32; rows stride 256 B)
  const uint8_t* Abase = Ap + (size_t)(rowBase + wm * 64 + fr) * D_DIM + fq * 32;
  const uint8_t* Bbase = Bp + (size_t)(nBase + wn * 64 + fr) * D_DIM + fq * 32;

  // sorted top-4 per accumulator slot, packed ((s+1024) bits & ~511) | col9
  uint32_t t1[4][4], t2[4][4], t3[4][4], t4[4][4];
#pragma unroll
  for (int i = 0; i < 4; ++i)
#pragma unroll
    for (int r = 0; r < 4; ++r) {
      t1[i][r] = 0x7f7ffe00u; t2[i][r] = 0x7f7ffe00u;
      t3[i][r] = 0x7f7ffe00u; t4[i][r] = 0x7f7ffe00u;
    }

  for (int nit = 0; nit < (K_CB / NSPLIT) / BN; ++nit) {   // 4 codeword tiles
    f32x4 acc[4][4];
#pragma unroll
    for (int i = 0; i < 4; ++i)
#pragma unroll
      for (int j = 0; j < 4; ++j) acc[i][j] = (f32x4){0.f, 0.f, 0.f, 0.f};

#pragma unroll
    for (int kh = 0; kh < 2; ++kh) {                       // two k=128 halves
      int8v af[4], bf[4];
#pragma unroll
      for (int i = 0; i < 4; ++i)                          // direct global->reg
        af[i] = *(const int8v*)(Abase + (size_t)(i * 16) * D_DIM + kh * 128);
#pragma unroll
      for (int j = 0; j < 4; ++j)
        bf[j] = *(const int8v*)(Bbase + (size_t)(nit * BN + j * 16) * D_DIM + kh * 128);
#pragma unroll
      for (int i = 0; i < 4; ++i)
#pragma unroll
        for (int j = 0; j < 4; ++j)
          acc[i][j] = __builtin_amdgcn_mfma_scale_f32_16x16x128_f8f6f4(
              af[i], bf[j], acc[i][j], 0, 0,       // cbsz=fp8, blgp=fp8
              0, 0x7f7f7f7f, 0, 0x7f7f7f7f);       // unit E8M0 scales
    }

    // epilogue: s = 1024 + c2[col] - 2*cross; pack; sorted top-4 insert (7 ops)
#pragma unroll
    for (int j = 0; j < 4; ++j) {
      const int col9 = nit * BN + wn * 64 + j * 16 + fr;   // 0..511 within split
      const float cv = c2[nBase + col9] + 1024.0f;         // shift: s always > 0
#pragma unroll
      for (int i = 0; i < 4; ++i)
#pragma unroll
        for (int r = 0; r < 4; ++r) {
          const float s = fmaf(-2.0f, acc[i][j][r], cv);
          const uint32_t p = (__float_as_uint(s) & ~511u) | (uint32_t)col9;
          const uint32_t b = umax32(t1[i][r], p); t1[i][r] = umin32(t1[i][r], p);
          const uint32_t d = umax32(t2[i][r], b); t2[i][r] = umin32(t2[i][r], b);
          const uint32_t f = umax32(t3[i][r], d); t3[i][r] = umin32(t3[i][r], d);
          t4[i][r] = umin32(t4[i][r], f);
        }
    }
  }

  // cross-lane merge of sorted-4 lists over the 16 fr lanes sharing each row
#pragma unroll
  for (int i = 0; i < 4; ++i)
#pragma unroll
    for (int r = 0; r < 4; ++r) {
      uint32_t a1 = t1[i][r], a2 = t2[i][r], a3 = t3[i][r], a4 = t4[i][r];
#pragma unroll
      for (int m = 1; m < 16; m <<= 1) {
        const uint32_t b1 = __shfl_xor(a1, m, 64);
        const uint32_t b2 = __shfl_xor(a2, m, 64);
        const uint32_t b3 = __shfl_xor(a3, m, 64);
        const uint32_t b4 = __shfl_xor(a4, m, 64);
        // bitonic lowest-4 of two ascending 4-lists, then bitonic sort-4
        uint32_t c1 = umin32(a1, b4), c2_ = umin32(a2, b3);
        uint32_t c3 = umin32(a3, b2), c4 = umin32(a4, b1);
        uint32_t lo, hi;
        lo = umin32(c1, c3); hi = umax32(c1, c3); c1 = lo; c3 = hi;
        lo = umin32(c2_, c4); hi = umax32(c2_, c4); c2_ = lo; c4 = hi;
        lo = umin32(c1, c2_); hi = umax32(c1, c2_); c1 = lo; c2_ = hi;
        lo = umin32(c3, c4); hi = umax32(c3, c4); c3 = lo; c4 = hi;
        a1 = c1; a2 = c2_; a3 = c3; a4 = c4;
      }
      if (fr == 0) {
        const int row = wm * 64 + i * 16 + fq * 4 + r;   // C/D layout (m89)
        sred[row][wn * 4 + 0] = a1; sred[row][wn * 4 + 1] = a2;
        sred[row][wn * 4 + 2] = a3; sred[row][wn * 4 + 3] = a4;
      }
    }
  __syncthreads();
  if (tid < BM) {
    uint32_t a1 = sred[tid][0], a2 = sred[tid][1], a3 = sred[tid][2], a4 = sred[tid][3];
    const uint32_t b1 = sred[tid][4], b2 = sred[tid][5], b3 = sred[tid][6], b4 = sred[tid][7];
    uint32_t c1 = umin32(a1, b4), c2_ = umin32(a2, b3);
    uint32_t c3 = umin32(a3, b2), c4 = umin32(a4, b1);
    uint32_t lo, hi;
    lo = umin32(c1, c3); hi = umax32(c1, c3); c1 = lo; c3 = hi;
    lo = umin32(c2_, c4); hi = umax32(c2_, c4); c2_ = lo; c4 = hi;
    lo = umin32(c1, c2_); hi = umax32(c1, c2_); c1 = lo; c2_ = hi;
    lo = umin32(c3, c4); hi = umax32(c3, c4); c3 = lo; c4 = hi;
    part[(size_t)(rowBase + tid) * NSPLIT + blockIdx.y] = make_uint4(c1, c2_, c3, c4);
  }
}

// -------- merge: 64 candidates/row -> certain winner or fp64 rescore --------
__global__ __launch_bounds__(256) void vq_merge(const uint32_t* __restrict__ part,
                                                const float* __restrict__ x,
                                                const float* __restrict__ cb,
                                                float* __restrict__ out) {
  const int w = threadIdx.x >> 6, lane = threadIdx.x & 63;
  const int row = blockIdx.x * 4 + w;                 // one wave per row

  const uint32_t pk = part[(size_t)row * 64 + lane];  // coalesced, 1 cand/lane
  const int gidx = (lane >> 2) * (K_CB / NSPLIT) + (int)(pk & 511u);

  // integer min == numeric min (all packed values positive)
  uint32_t pmin = pk;
#pragma unroll
  for (int m = 1; m < 64; m <<= 1) {
    const uint32_t o = __shfl_xor(pmin, m, 64);
    pmin = pmin < o ? pmin : o;
  }
  const float vmin = __uint_as_float(pmin & ~511u);
  const float vme  = __uint_as_float(pk & ~511u);
  const unsigned long long mask = __ballot(vme <= vmin + EPS);

  const f32x4 xv = *(const f32x4*)(x + (size_t)row * D_DIM + lane * 4);

  int winner;
  if (__popcll(mask) == 1) {
    winner = __shfl(gidx, __ffsll((long long)mask) - 1, 64);
  } else {
    // exact fp64 rescore of the qualifiers (ties -> smaller index, like np)
    double bestd = 1.0e300;
    int bidx = 0x7fffffff;
    unsigned long long mm = mask;
    while (mm) {
      const int q = __ffsll((long long)mm) - 1;
      mm &= mm - 1;
      const int ci = __shfl(gidx, q, 64);
      const f32x4 cv = *(const f32x4*)(cb + (size_t)ci * D_DIM + lane * 4);
      double s = 0.0;
#pragma unroll
      for (int t = 0; t < 4; ++t) {
        const double dx = (double)xv[t] - (double)cv[t];
        s += dx * dx;
      }
#pragma unroll
      for (int m = 1; m < 64; m <<= 1) s += __shfl_xor(s, m, 64);
      if (s < bestd || (s == bestd && ci < bidx)) { bestd = s; bidx = ci; }
    }
    winner = bidx;
  }

  float* out_recon = out;
  float* out_ze    = out + (size_t)M_ROWS * D_DIM;
  float* out_zq    = out + 2 * (size_t)M_ROWS * D_DIM;
  float* out_idx   = out + 3 * (size_t)M_ROWS * D_DIM;

  const f32x4 cv = *(const f32x4*)(cb + (size_t)winner * D_DIM + lane * 4);
  *(f32x4*)(out_recon + (size_t)row * D_DIM + lane * 4) = cv;  // identity decoder
  *(f32x4*)(out_zq    + (size_t)row * D_DIM + lane * 4) = cv;
  *(f32x4*)(out_ze    + (size_t)row * D_DIM + lane * 4) = xv;  // identity encoder
  if (lane == 0) out_idx[row] = (float)winner;
}

extern "C" void kernel_launch(void* const* d_in, const int* in_sizes, int n_in,
                              void* d_out, int out_size, void* d_ws, size_t ws_size,
                              hipStream_t stream) {
  const float* x  = (const float*)d_in[0];
  const float* cb = (const float*)d_in[1];
  float* out = (float*)d_out;

  // ws: c2 (32 KB) | part uint4[16384][16] (4 MB) | Ap fp8 (4 MB) | Bp fp8 (2 MB)
  char* ws = (char*)d_ws;
  float*    c2   = (float*)ws;
  uint4*    part = (uint4*)(ws + 32768);
  uint8_t*  Ap   = (uint8_t*)(ws + 32768 + 4194304);
  uint8_t*  Bp   = Ap + (size_t)M_ROWS * D_DIM;
  if (ws_size < (size_t)(32768 + 4194304 + 4194304 + 2097152)) return;

  prep    <<<dim3(M_ROWS / 4 + K_CB / 4), dim3(256), 0, stream>>>(x, cb, Ap, Bp, c2);
  vq_main <<<dim3(M_ROWS / BM, NSPLIT), dim3(256), 0, stream>>>(Ap, Bp, c2, part);
  vq_merge<<<dim3(M_ROWS / 4), dim3(256), 0, stream>>>((const uint32_t*)part, x, cb, out);
}